// Round 4
// baseline (11827.375 us; speedup 1.0000x reference)
//
#include <hip/hip_runtime.h>
#include <math.h>

#define LATENT   1024
#define WORD     64
#define NB_WORD  8192
#define BATCH    2048
#define NROWS    (BATCH * LATENT / WORD)   // 32768
#define NELEM    (BATCH * LATENT)          // 2097152

#define BM       64                        // rows per block
#define BN       128                       // codewords per tile
#define NT       (NB_WORD / BN)            // 64 tiles

// ---------------- kernel 1: e2[m] = sum_k emb[m][k]^2 ----------------
__global__ __launch_bounds__(256) void vq_e2_kernel(
    const float* __restrict__ emb, float* __restrict__ e2) {
    int m = blockIdx.x * 256 + threadIdx.x;
    if (m >= NB_WORD) return;
    const float4* ep = reinterpret_cast<const float4*>(emb + (size_t)m * WORD);
    float s0 = 0.f, s1 = 0.f, s2 = 0.f, s3 = 0.f;
#pragma unroll
    for (int i = 0; i < 16; ++i) {
        float4 v = ep[i];
        s0 = fmaf(v.x, v.x, s0);
        s1 = fmaf(v.y, v.y, s1);
        s2 = fmaf(v.z, v.z, s2);
        s3 = fmaf(v.w, v.w, s3);
    }
    e2[m] = (s0 + s1) + (s2 + s3);
}

__device__ __forceinline__ void gload_lds16(const float* g, float* l) {
    __builtin_amdgcn_global_load_lds(
        (const __attribute__((address_space(1))) void*)g,
        (__attribute__((address_space(3))) void*)l, 16, 0, 0);
}
__device__ __forceinline__ void gload_lds4(const float* g, float* l) {
    __builtin_amdgcn_global_load_lds(
        (const __attribute__((address_space(1))) void*)g,
        (__attribute__((address_space(3))) void*)l, 4, 0, 0);
}

// ---------------- kernel 2: tiled register-blocked argmin -------------
// 256 threads. c = tid&15, rl = tid>>4. Thread owns rows rl*4..+3 x cw c+16s.
// lz: f4-slot row*16 + kk^(row&15) (ds_write staged, once).
// le: dbuf[h] of half-K tiles, f4-slot cw*8 + kk^(cw&7), filled by
// global_load_lds with pre-swizzled global source (linear LDS dest).
__global__ __launch_bounds__(256, 3) void vq_argmin_kernel(
    const float* __restrict__ z, const float* __restrict__ emb,
    const float* __restrict__ e2, unsigned long long* __restrict__ best) {

    __shared__ float lz[BM * 64];          // 16 KB
    __shared__ float le[2][BN * 32];       // 2 x 16 KB
    __shared__ float le2[2][BN];           // 2 x 512 B

    const int tid = threadIdx.x;
    const int c   = tid & 15;
    const int rl  = tid >> 4;              // 0..15
    const int rowbase = blockIdx.x * BM;

    // ---- stage z (swizzled ds_write, once) ----
#pragma unroll
    for (int j = 0; j < 4; ++j) {
        int slot = j * 256 + tid;          // f4 slot 0..1023
        int row = slot >> 4, kk = slot & 15;
        float4 v = reinterpret_cast<const float4*>(z)[(size_t)(rowbase + row) * 16 + kk];
        *reinterpret_cast<float4*>(&lz[(row * 16 + (kk ^ (row & 15))) * 4]) = v;
    }

    // ---- stage e half0 of tile 0 -> le[0]; e2 tile 0 -> le2[0] ----
#pragma unroll
    for (int j = 0; j < 4; ++j) {
        int slot = j * 256 + tid;          // f4 slot in half-tile
        int cw = slot >> 3, kk = slot & 7;
        gload_lds16(emb + ((size_t)cw * 16 + (kk ^ (cw & 7))) * 4,
                    &le[0][(size_t)(j * 256 + (tid & ~63)) * 4]);
    }
    if (tid < BN)
        gload_lds4(e2 + tid, &le2[0][tid & ~63]);
    __syncthreads();

    // ---- per-thread z2 for its 4 rows ----
    float z2v[4];
#pragma unroll
    for (int i = 0; i < 4; ++i) {
        int row = rl * 4 + i;
        float a0 = 0.f, a1 = 0.f, a2 = 0.f, a3 = 0.f;
#pragma unroll
        for (int g = 0; g < 16; ++g) {
            float4 v = *reinterpret_cast<const float4*>(
                &lz[(row * 16 + (g ^ (row & 15))) * 4]);
            a0 = fmaf(v.x, v.x, a0);
            a1 = fmaf(v.y, v.y, a1);
            a2 = fmaf(v.z, v.z, a2);
            a3 = fmaf(v.w, v.w, a3);
        }
        z2v[i] = (a0 + a1) + (a2 + a3);
    }

    float bestd[4] = {INFINITY, INFINITY, INFINITY, INFINITY};
    int   bestm[4] = {0, 0, 0, 0};
    float acc[4][8];

    for (int t = 0; t < NT; ++t) {
        // ================= phase A: half 0 (le[0]) =================
        // stage half 1 of tile t -> le[1]
#pragma unroll
        for (int j = 0; j < 4; ++j) {
            int slot = j * 256 + tid;
            int cw = slot >> 3, kk = slot & 7;
            gload_lds16(emb + ((size_t)(t * BN + cw) * 16 + 8 + (kk ^ (cw & 7))) * 4,
                        &le[1][(size_t)(j * 256 + (tid & ~63)) * 4]);
        }
#pragma unroll
        for (int i = 0; i < 4; ++i)
#pragma unroll
            for (int s = 0; s < 8; ++s) acc[i][s] = 0.f;

#pragma unroll
        for (int g = 0; g < 8; ++g) {
            float4 za[4];
#pragma unroll
            for (int i = 0; i < 4; ++i) {
                int row = rl * 4 + i;
                za[i] = *reinterpret_cast<const float4*>(
                    &lz[(row * 16 + (g ^ (row & 15))) * 4]);
            }
#pragma unroll
            for (int s = 0; s < 8; ++s) {
                float4 ev = *reinterpret_cast<const float4*>(
                    &le[0][((c + 16 * s) * 8 + (g ^ (c & 7))) * 4]);
#pragma unroll
                for (int i = 0; i < 4; ++i) {
                    acc[i][s] = fmaf(za[i].x, ev.x, acc[i][s]);
                    acc[i][s] = fmaf(za[i].y, ev.y, acc[i][s]);
                    acc[i][s] = fmaf(za[i].z, ev.z, acc[i][s]);
                    acc[i][s] = fmaf(za[i].w, ev.w, acc[i][s]);
                }
            }
        }
        __syncthreads();

        // ================= phase B: half 1 (le[1]) =================
        // stage half 0 of tile t+1 -> le[0]; e2 of tile t+1 -> le2[(t+1)&1]
        if (t + 1 < NT) {
#pragma unroll
            for (int j = 0; j < 4; ++j) {
                int slot = j * 256 + tid;
                int cw = slot >> 3, kk = slot & 7;
                gload_lds16(emb + ((size_t)((t + 1) * BN + cw) * 16 + (kk ^ (cw & 7))) * 4,
                            &le[0][(size_t)(j * 256 + (tid & ~63)) * 4]);
            }
            if (tid < BN)
                gload_lds4(e2 + (t + 1) * BN + tid, &le2[(t + 1) & 1][tid & ~63]);
        }

#pragma unroll
        for (int g = 0; g < 8; ++g) {
            const int gg = 8 + g;
            float4 za[4];
#pragma unroll
            for (int i = 0; i < 4; ++i) {
                int row = rl * 4 + i;
                za[i] = *reinterpret_cast<const float4*>(
                    &lz[(row * 16 + (gg ^ (row & 15))) * 4]);
            }
#pragma unroll
            for (int s = 0; s < 8; ++s) {
                float4 ev = *reinterpret_cast<const float4*>(
                    &le[1][((c + 16 * s) * 8 + (g ^ (c & 7))) * 4]);
#pragma unroll
                for (int i = 0; i < 4; ++i) {
                    acc[i][s] = fmaf(za[i].x, ev.x, acc[i][s]);
                    acc[i][s] = fmaf(za[i].y, ev.y, acc[i][s]);
                    acc[i][s] = fmaf(za[i].z, ev.z, acc[i][s]);
                    acc[i][s] = fmaf(za[i].w, ev.w, acc[i][s]);
                }
            }
        }

        // ---- fold argmin for tile t ----
#pragma unroll
        for (int s = 0; s < 8; ++s) {
            int   m   = t * BN + c + 16 * s;
            float e2m = le2[t & 1][c + 16 * s];
#pragma unroll
            for (int i = 0; i < 4; ++i) {
                float d = fmaf(-2.0f, acc[i][s], z2v[i] + e2m);
                if (d < bestd[i]) { bestd[i] = d; bestm[i] = m; }
            }
        }
        __syncthreads();
    }

    // ---- cross-lane min over the 16 c-lanes sharing each row ----
#pragma unroll
    for (int i = 0; i < 4; ++i) {
        unsigned int db = __float_as_uint(bestd[i]);
        db = (db & 0x80000000u) ? ~db : (db | 0x80000000u);
        unsigned long long key =
            ((unsigned long long)db << 32) | (unsigned int)bestm[i];
#pragma unroll
        for (int off = 1; off < 16; off <<= 1) {
            unsigned long long o = __shfl_xor(key, off);
            key = (o < key) ? o : key;
        }
        if (c == 0) best[rowbase + rl * 4 + i] = key;
    }
}

// ---------------- kernel 3: gather + straight-through output + loss ---
__global__ __launch_bounds__(256) void vq_out_kernel(
    const float* __restrict__ z, const float* __restrict__ emb,
    const unsigned long long* __restrict__ best,
    float* __restrict__ out, float* __restrict__ lsum) {
    const int base = (blockIdx.x * 256 + threadIdx.x) * 8;   // 8 elems/thread
    const int row  = base >> 6;
    const int m    = (int)(best[row] & 0xFFFFFFFFull);

    const float4* zp = reinterpret_cast<const float4*>(z + base);
    const float4* qp = reinterpret_cast<const float4*>(emb + (size_t)m * WORD + (base & 63));
    float4* op = reinterpret_cast<float4*>(out + base);

    float s = 0.f;
#pragma unroll
    for (int i = 0; i < 2; ++i) {
        float4 zv = zp[i];
        float4 qv = qp[i];
        float dx = qv.x - zv.x, dy = qv.y - zv.y, dz = qv.z - zv.z, dw = qv.w - zv.w;
        float4 ov;
        ov.x = zv.x + dx; ov.y = zv.y + dy; ov.z = zv.z + dz; ov.w = zv.w + dw;
        op[i] = ov;
        s += dx*dx + dy*dy + dz*dz + dw*dw;
    }

#pragma unroll
    for (int off = 32; off > 0; off >>= 1) s += __shfl_down(s, off);
    __shared__ float wsum[4];
    int lane = threadIdx.x & 63, wid = threadIdx.x >> 6;
    if (lane == 0) wsum[wid] = s;
    __syncthreads();
    if (threadIdx.x == 0)
        atomicAdd(lsum, (wsum[0] + wsum[1]) + (wsum[2] + wsum[3]));
}

// ---------------- kernel 4: finalize loss -----------------------------
__global__ void vq_loss_kernel(const float* __restrict__ lsum,
                               float* __restrict__ loss_out) {
    float mean = lsum[0] * (1.0f / (float)NELEM);
    loss_out[0] = mean + 2.5f * mean;
}

extern "C" void kernel_launch(void* const* d_in, const int* in_sizes, int n_in,
                              void* d_out, int out_size, void* d_ws, size_t ws_size,
                              hipStream_t stream) {
    const float* z   = (const float*)d_in[0];   // z_mean (2048,1024)
    // d_in[1] = z_log_var, unused by the reference
    const float* emb = (const float*)d_in[2];   // (8192,64)
    float* out = (float*)d_out;                 // [z_q_st flat (2097152), loss]

    float* e2 = (float*)d_ws;
    unsigned long long* best =
        (unsigned long long*)((char*)d_ws + NB_WORD * sizeof(float));
    float* lsum = (float*)((char*)best + NROWS * sizeof(unsigned long long));

    hipMemsetAsync(lsum, 0, sizeof(float), stream);

    vq_e2_kernel<<<NB_WORD / 256, 256, 0, stream>>>(emb, e2);
    vq_argmin_kernel<<<NROWS / BM, 256, 0, stream>>>(z, emb, e2, best);
    vq_out_kernel<<<NELEM / (256 * 8), 256, 0, stream>>>(z, emb, best, out, lsum);
    vq_loss_kernel<<<1, 1, 0, stream>>>(lsum, out + NELEM);
}

// Round 5
// 6051.250 us; speedup vs baseline: 1.9545x; 1.9545x over previous
//
#include <hip/hip_runtime.h>
#include <math.h>

#define LATENT   1024
#define WORD     64
#define NB_WORD  8192
#define BATCH    2048
#define NROWS    (BATCH * LATENT / WORD)   // 32768
#define NELEM    (BATCH * LATENT)          // 2097152

#define BM       128                       // rows per block
#define BN       256                       // codewords per tile
#define NT       (NB_WORD / BN)            // 32 tiles

// ---------------- kernel 1: e2[m] = sum_k emb[m][k]^2 ----------------
__global__ __launch_bounds__(256) void vq_e2_kernel(
    const float* __restrict__ emb, float* __restrict__ e2) {
    int m = blockIdx.x * 256 + threadIdx.x;
    if (m >= NB_WORD) return;
    const float4* ep = reinterpret_cast<const float4*>(emb + (size_t)m * WORD);
    float s0 = 0.f, s1 = 0.f, s2 = 0.f, s3 = 0.f;
#pragma unroll
    for (int i = 0; i < 16; ++i) {
        float4 v = ep[i];
        s0 = fmaf(v.x, v.x, s0);
        s1 = fmaf(v.y, v.y, s1);
        s2 = fmaf(v.z, v.z, s2);
        s3 = fmaf(v.w, v.w, s3);
    }
    e2[m] = (s0 + s1) + (s2 + s3);
}

__device__ __forceinline__ void gload_lds16(const float* g, float* l) {
    __builtin_amdgcn_global_load_lds(
        (const __attribute__((address_space(1))) void*)g,
        (__attribute__((address_space(3))) void*)l, 16, 0, 0);
}
__device__ __forceinline__ void gload_lds4(const float* g, float* l) {
    __builtin_amdgcn_global_load_lds(
        (const __attribute__((address_space(1))) void*)g,
        (__attribute__((address_space(3))) void*)l, 4, 0, 0);
}

// ---------------- kernel 2: tiled register-blocked argmin -------------
// 512 threads. c = tid&31, rl = tid>>5. Thread owns rows rl*8+i (i<8) x
// codewords c+32s (s<8). 8x8 accumulator micro-tile (64 VGPRs) -- budget
// pinned to 256 VGPRs via amdgpu_waves_per_eu(2,2).
// lz: [128 rows][16 f4] LINEAR (za reads are 2-addr broadcasts).
// le: dbuf half-K tiles [256 cw][8 f4], slot kk^(cw&7), filled by
// global_load_lds with pre-swizzled global source (linear LDS dest).
__global__ __launch_bounds__(512)
__attribute__((amdgpu_waves_per_eu(2, 2)))
void vq_argmin_kernel(
    const float* __restrict__ z, const float* __restrict__ emb,
    const float* __restrict__ e2, unsigned long long* __restrict__ best) {

    __shared__ float lz[BM * 64];          // 32 KB
    __shared__ float le[2][BN * 32];       // 2 x 32 KB
    __shared__ float le2[2][BN];           // 2 x 1 KB

    const int tid = threadIdx.x;
    const int c   = tid & 31;              // codeword lane 0..31
    const int rl  = tid >> 5;              // row group 0..15
    const int rowbase = blockIdx.x * BM;

    // ---- stage z (linear, async): slot = row*16 + kk ----
#pragma unroll
    for (int j = 0; j < 4; ++j) {
        int slot = j * 512 + tid;          // f4 slot 0..2047
        gload_lds16(z + (size_t)rowbase * 64 + (size_t)slot * 4,
                    &lz[(size_t)(j * 512 + (tid & ~63)) * 4]);
    }
    // ---- stage e half0 of tile 0 -> le[0]; e2 tile 0 -> le2[0] ----
#pragma unroll
    for (int j = 0; j < 4; ++j) {
        int slot = j * 512 + tid;          // f4 slot in half-tile
        int cw = slot >> 3, kk = slot & 7;
        gload_lds16(emb + ((size_t)cw * 16 + (kk ^ (cw & 7))) * 4,
                    &le[0][(size_t)(j * 512 + (tid & ~63)) * 4]);
    }
    if (tid < BN)
        gload_lds4(e2 + tid, &le2[0][tid & ~63]);
    __syncthreads();

    // ---- per-thread z2 for its 8 rows (same chain order as r1-r4) ----
    float z2v[8];
#pragma unroll
    for (int i = 0; i < 8; ++i) {
        int row = rl * 8 + i;
        float a0 = 0.f, a1 = 0.f, a2 = 0.f, a3 = 0.f;
#pragma unroll
        for (int g = 0; g < 16; ++g) {
            float4 v = *reinterpret_cast<const float4*>(&lz[(row * 16 + g) * 4]);
            a0 = fmaf(v.x, v.x, a0);
            a1 = fmaf(v.y, v.y, a1);
            a2 = fmaf(v.z, v.z, a2);
            a3 = fmaf(v.w, v.w, a3);
        }
        z2v[i] = (a0 + a1) + (a2 + a3);
    }

    float bestd[8] = {INFINITY, INFINITY, INFINITY, INFINITY,
                      INFINITY, INFINITY, INFINITY, INFINITY};
    int   bestm[8] = {0, 0, 0, 0, 0, 0, 0, 0};
    float acc[8][8];
    const int esw = c & 7;                 // read-side swizzle (s-independent)

    for (int t = 0; t < NT; ++t) {
        // ================= phase A: half 0 (le[0]) =================
        // stage half 1 of tile t -> le[1]
#pragma unroll
        for (int j = 0; j < 4; ++j) {
            int slot = j * 512 + tid;
            int cw = slot >> 3, kk = slot & 7;
            gload_lds16(emb + ((size_t)(t * BN + cw) * 16 + 8 + (kk ^ (cw & 7))) * 4,
                        &le[1][(size_t)(j * 512 + (tid & ~63)) * 4]);
        }
#pragma unroll
        for (int i = 0; i < 8; ++i)
#pragma unroll
            for (int s = 0; s < 8; ++s) acc[i][s] = 0.f;

#pragma unroll
        for (int g = 0; g < 8; ++g) {
            float4 ev[8];
#pragma unroll
            for (int s = 0; s < 8; ++s)
                ev[s] = *reinterpret_cast<const float4*>(
                    &le[0][((c + 32 * s) * 8 + (g ^ esw)) * 4]);
#pragma unroll
            for (int i = 0; i < 8; ++i) {
                float4 za = *reinterpret_cast<const float4*>(
                    &lz[((rl * 8 + i) * 16 + g) * 4]);
#pragma unroll
                for (int s = 0; s < 8; ++s) {
                    acc[i][s] = fmaf(za.x, ev[s].x, acc[i][s]);
                    acc[i][s] = fmaf(za.y, ev[s].y, acc[i][s]);
                    acc[i][s] = fmaf(za.z, ev[s].z, acc[i][s]);
                    acc[i][s] = fmaf(za.w, ev[s].w, acc[i][s]);
                }
            }
        }
        __syncthreads();

        // ================= phase B: half 1 (le[1]) =================
        // stage half 0 of tile t+1 -> le[0]; e2 of tile t+1 -> le2[(t+1)&1]
        if (t + 1 < NT) {
#pragma unroll
            for (int j = 0; j < 4; ++j) {
                int slot = j * 512 + tid;
                int cw = slot >> 3, kk = slot & 7;
                gload_lds16(emb + ((size_t)((t + 1) * BN + cw) * 16 + (kk ^ (cw & 7))) * 4,
                            &le[0][(size_t)(j * 512 + (tid & ~63)) * 4]);
            }
            if (tid < BN)
                gload_lds4(e2 + (t + 1) * BN + tid, &le2[(t + 1) & 1][tid & ~63]);
        }

#pragma unroll
        for (int g = 0; g < 8; ++g) {
            float4 ev[8];
#pragma unroll
            for (int s = 0; s < 8; ++s)
                ev[s] = *reinterpret_cast<const float4*>(
                    &le[1][((c + 32 * s) * 8 + (g ^ esw)) * 4]);
#pragma unroll
            for (int i = 0; i < 8; ++i) {
                float4 za = *reinterpret_cast<const float4*>(
                    &lz[((rl * 8 + i) * 16 + 8 + g) * 4]);
#pragma unroll
                for (int s = 0; s < 8; ++s) {
                    acc[i][s] = fmaf(za.x, ev[s].x, acc[i][s]);
                    acc[i][s] = fmaf(za.y, ev[s].y, acc[i][s]);
                    acc[i][s] = fmaf(za.z, ev[s].z, acc[i][s]);
                    acc[i][s] = fmaf(za.w, ev[s].w, acc[i][s]);
                }
            }
        }

        // ---- fold argmin for tile t ----
#pragma unroll
        for (int s = 0; s < 8; ++s) {
            int   m   = t * BN + c + 32 * s;
            float e2m = le2[t & 1][c + 32 * s];
#pragma unroll
            for (int i = 0; i < 8; ++i) {
                float d = fmaf(-2.0f, acc[i][s], z2v[i] + e2m);
                if (d < bestd[i]) { bestd[i] = d; bestm[i] = m; }
            }
        }
        __syncthreads();
    }

    // ---- cross-lane min over the 32 c-lanes sharing each row ----
#pragma unroll
    for (int i = 0; i < 8; ++i) {
        unsigned int db = __float_as_uint(bestd[i]);
        db = (db & 0x80000000u) ? ~db : (db | 0x80000000u);
        unsigned long long key =
            ((unsigned long long)db << 32) | (unsigned int)bestm[i];
#pragma unroll
        for (int off = 1; off < 32; off <<= 1) {
            unsigned long long o = __shfl_xor(key, off);
            key = (o < key) ? o : key;
        }
        if (c == 0) best[rowbase + rl * 8 + i] = key;
    }
}

// ---------------- kernel 3: gather + straight-through output + loss ---
__global__ __launch_bounds__(256) void vq_out_kernel(
    const float* __restrict__ z, const float* __restrict__ emb,
    const unsigned long long* __restrict__ best,
    float* __restrict__ out, float* __restrict__ lsum) {
    const int base = (blockIdx.x * 256 + threadIdx.x) * 8;   // 8 elems/thread
    const int row  = base >> 6;
    const int m    = (int)(best[row] & 0xFFFFFFFFull);

    const float4* zp = reinterpret_cast<const float4*>(z + base);
    const float4* qp = reinterpret_cast<const float4*>(emb + (size_t)m * WORD + (base & 63));
    float4* op = reinterpret_cast<float4*>(out + base);

    float s = 0.f;
#pragma unroll
    for (int i = 0; i < 2; ++i) {
        float4 zv = zp[i];
        float4 qv = qp[i];
        float dx = qv.x - zv.x, dy = qv.y - zv.y, dz = qv.z - zv.z, dw = qv.w - zv.w;
        float4 ov;
        ov.x = zv.x + dx; ov.y = zv.y + dy; ov.z = zv.z + dz; ov.w = zv.w + dw;
        op[i] = ov;
        s += dx*dx + dy*dy + dz*dz + dw*dw;
    }

#pragma unroll
    for (int off = 32; off > 0; off >>= 1) s += __shfl_down(s, off);
    __shared__ float wsum[4];
    int lane = threadIdx.x & 63, wid = threadIdx.x >> 6;
    if (lane == 0) wsum[wid] = s;
    __syncthreads();
    if (threadIdx.x == 0)
        atomicAdd(lsum, (wsum[0] + wsum[1]) + (wsum[2] + wsum[3]));
}

// ---------------- kernel 4: finalize loss -----------------------------
__global__ void vq_loss_kernel(const float* __restrict__ lsum,
                               float* __restrict__ loss_out) {
    float mean = lsum[0] * (1.0f / (float)NELEM);
    loss_out[0] = mean + 2.5f * mean;
}

extern "C" void kernel_launch(void* const* d_in, const int* in_sizes, int n_in,
                              void* d_out, int out_size, void* d_ws, size_t ws_size,
                              hipStream_t stream) {
    const float* z   = (const float*)d_in[0];   // z_mean (2048,1024)
    // d_in[1] = z_log_var, unused by the reference
    const float* emb = (const float*)d_in[2];   // (8192,64)
    float* out = (float*)d_out;                 // [z_q_st flat (2097152), loss]

    float* e2 = (float*)d_ws;
    unsigned long long* best =
        (unsigned long long*)((char*)d_ws + NB_WORD * sizeof(float));
    float* lsum = (float*)((char*)best + NROWS * sizeof(unsigned long long));

    hipMemsetAsync(lsum, 0, sizeof(float), stream);

    vq_e2_kernel<<<NB_WORD / 256, 256, 0, stream>>>(emb, e2);
    vq_argmin_kernel<<<NROWS / BM, 512, 0, stream>>>(z, emb, e2, best);
    vq_out_kernel<<<NELEM / (256 * 8), 256, 0, stream>>>(z, emb, best, out, lsum);
    vq_loss_kernel<<<1, 1, 0, stream>>>(lsum, out + NELEM);
}

// Round 6
// 204.917 us; speedup vs baseline: 57.7179x; 29.5303x over previous
//
#include <hip/hip_runtime.h>
#include <math.h>

#define LATENT   1024
#define WORD     64
#define NB_WORD  8192
#define BATCH    2048
#define NROWS    (BATCH * LATENT / WORD)   // 32768
#define NELEM    (BATCH * LATENT)          // 2097152

#define NCHUNK   4
#define CWCHUNK  (NB_WORD / NCHUNK)        // 2048
#define TPC      (CWCHUNK / 16)            // 128 tiles per chunk
#define NTILE    (NB_WORD / 16)            // 512 tiles
#define PKTS     (NTILE * 6 * 64)          // 196608 16B packets

typedef __attribute__((ext_vector_type(8))) __bf16 bf16x8;
typedef __attribute__((ext_vector_type(4))) float  f32x4;

// ---------------- kernel 1: e2[m] = sum_k emb[m][k]^2 (r1-proven) -----
__global__ __launch_bounds__(256) void vq_e2_kernel(
    const float* __restrict__ emb, float* __restrict__ e2) {
    int m = blockIdx.x * 256 + threadIdx.x;
    if (m >= NB_WORD) return;
    const float4* ep = reinterpret_cast<const float4*>(emb + (size_t)m * WORD);
    float s0 = 0.f, s1 = 0.f, s2 = 0.f, s3 = 0.f;
#pragma unroll
    for (int i = 0; i < 16; ++i) {
        float4 v = ep[i];
        s0 = fmaf(v.x, v.x, s0);
        s1 = fmaf(v.y, v.y, s1);
        s2 = fmaf(v.z, v.z, s2);
        s3 = fmaf(v.w, v.w, s3);
    }
    e2[m] = (s0 + s1) + (s2 + s3);
}

// ---------------- kernel 1b: pack e-splits in MFMA fragment order -----
// packet p = (tile*6 + spl*2 + Ks)*64 + lane ; 16 bytes = 8 bf16 of split
// level spl for (cw = tile*16 + (lane&15), k = Ks*32 + (lane>>4)*8 + e).
__global__ __launch_bounds__(256) void vq_epack_kernel(
    const float* __restrict__ emb, bf16x8* __restrict__ epack) {
    int p = blockIdx.x * 256 + threadIdx.x;    // 0..196607
    int lane = p & 63;
    int q    = p >> 6;
    int Ks   = q & 1;
    int r    = q >> 1;
    int spl  = r % 3;
    int tile = r / 3;
    int cw = tile * 16 + (lane & 15);
    int k0 = Ks * 32 + (lane >> 4) * 8;
    const float4* s4 = reinterpret_cast<const float4*>(emb + (size_t)cw * WORD + k0);
    float4 a = s4[0], b = s4[1];
    float tv[8] = {a.x, a.y, a.z, a.w, b.x, b.y, b.z, b.w};
    bf16x8 o;
#pragma unroll
    for (int e = 0; e < 8; ++e) {
        float v = tv[e];
        __bf16 h  = (__bf16)v;
        float r1  = v - (float)h;
        __bf16 m  = (__bf16)r1;
        float r2  = r1 - (float)m;
        __bf16 lo = (__bf16)r2;
        o[e] = (spl == 0) ? h : ((spl == 1) ? m : lo);
    }
    epack[p] = o;
}

__device__ __forceinline__ void gload_lds16(const char* g, char* l) {
    __builtin_amdgcn_global_load_lds(
        (const __attribute__((address_space(1))) void*)g,
        (__attribute__((address_space(3))) void*)l, 16, 0, 0);
}

// ---------------- kernel 2: MFMA split-bf16 argmin --------------------
// 256 thr = 4 waves; block = 128 rows x 2048-cw chunk; wave = 32 rows.
// Per iter (16 cw): DMA next tile (6 KB), 6 ds_read_b128 B-frags,
// 24 mfma_f32_16x16x32_bf16 (6 split-combos x 2 Ksteps x 2 mtiles),
// fold score = e2 - 2*dot into per-lane running argmin.
__global__ __launch_bounds__(256, 2)
__attribute__((amdgpu_waves_per_eu(2, 4)))
void vq_argmin_kernel(
    const float* __restrict__ z, const bf16x8* __restrict__ epack,
    const float* __restrict__ e2, unsigned long long* __restrict__ best) {

    __shared__ __align__(16) char le[2 * 6144];

    const int tid   = threadIdx.x;
    const int lane  = tid & 63;
    const int wband = tid >> 6;               // 0..3
    const int l15   = lane & 15;
    const int l4    = lane >> 4;              // 0..3
    const int rowbase   = blockIdx.x * 128 + wband * 32;
    const int tile0     = blockIdx.y * TPC;
    const int chunkbase = blockIdx.y * CWCHUNK;

    // ---- stage tile 0 into buf 0 ----
    {
        const char* src = (const char*)epack + (size_t)tile0 * 6144 + tid * 16;
        char* dst = le + (tid & ~63) * 16;
        gload_lds16(src, dst);
        if (tid < 128) gload_lds16(src + 4096, dst + 4096);
    }

    // ---- build A-frags (z 3-way bf16 split) in registers ----
    bf16x8 A[2][2][3];                         // [mt][Ks][spl]
    const float4* zf4 = reinterpret_cast<const float4*>(z);
#pragma unroll
    for (int mt = 0; mt < 2; ++mt) {
        int row = rowbase + mt * 16 + l15;
#pragma unroll
        for (int Ks = 0; Ks < 2; ++Ks) {
            float4 v0 = zf4[(size_t)row * 16 + Ks * 8 + l4 * 2];
            float4 v1 = zf4[(size_t)row * 16 + Ks * 8 + l4 * 2 + 1];
            float tv[8] = {v0.x, v0.y, v0.z, v0.w, v1.x, v1.y, v1.z, v1.w};
#pragma unroll
            for (int e = 0; e < 8; ++e) {
                float v = tv[e];
                __bf16 h  = (__bf16)v;
                float r1  = v - (float)h;
                __bf16 m  = (__bf16)r1;
                float r2  = r1 - (float)m;
                __bf16 lo = (__bf16)r2;
                A[mt][Ks][0][e] = h;
                A[mt][Ks][1][e] = m;
                A[mt][Ks][2][e] = lo;
            }
        }
    }
    __syncthreads();

    float bestd[8] = {INFINITY, INFINITY, INFINITY, INFINITY,
                      INFINITY, INFINITY, INFINITY, INFINITY};
    unsigned bp0 = 0u, bp1 = 0u;               // packed iter idx, 8b per v

    for (int t = 0; t < TPC; ++t) {
        const int buf = t & 1;
        // DMA next tile into the other buffer (overlaps compute)
        if (t + 1 < TPC) {
            const char* src = (const char*)epack +
                              (size_t)(tile0 + t + 1) * 6144 + tid * 16;
            char* dst = le + (buf ^ 1) * 6144 + (tid & ~63) * 16;
            gload_lds16(src, dst);
            if (tid < 128) gload_lds16(src + 4096, dst + 4096);
        }
        float e2v = e2[chunkbase + t * 16 + l15];

        f32x4 acc0 = {0.f, 0.f, 0.f, 0.f};
        f32x4 acc1 = {0.f, 0.f, 0.f, 0.f};
#pragma unroll
        for (int Ks = 0; Ks < 2; ++Ks) {
            const char* bbase = le + buf * 6144 + (size_t)Ks * 1024 + lane * 16;
            bf16x8 Bh = *reinterpret_cast<const bf16x8*>(bbase);          // spl0
            bf16x8 Bm = *reinterpret_cast<const bf16x8*>(bbase + 2048);   // spl1
            bf16x8 Bl = *reinterpret_cast<const bf16x8*>(bbase + 4096);   // spl2
            // combos: hh, mh, lh, hm, mm, hl  (x 2 row-tiles)
            acc0 = __builtin_amdgcn_mfma_f32_16x16x32_bf16(A[0][Ks][0], Bh, acc0, 0, 0, 0);
            acc1 = __builtin_amdgcn_mfma_f32_16x16x32_bf16(A[1][Ks][0], Bh, acc1, 0, 0, 0);
            acc0 = __builtin_amdgcn_mfma_f32_16x16x32_bf16(A[0][Ks][1], Bh, acc0, 0, 0, 0);
            acc1 = __builtin_amdgcn_mfma_f32_16x16x32_bf16(A[1][Ks][1], Bh, acc1, 0, 0, 0);
            acc0 = __builtin_amdgcn_mfma_f32_16x16x32_bf16(A[0][Ks][2], Bh, acc0, 0, 0, 0);
            acc1 = __builtin_amdgcn_mfma_f32_16x16x32_bf16(A[1][Ks][2], Bh, acc1, 0, 0, 0);
            acc0 = __builtin_amdgcn_mfma_f32_16x16x32_bf16(A[0][Ks][0], Bm, acc0, 0, 0, 0);
            acc1 = __builtin_amdgcn_mfma_f32_16x16x32_bf16(A[1][Ks][0], Bm, acc1, 0, 0, 0);
            acc0 = __builtin_amdgcn_mfma_f32_16x16x32_bf16(A[0][Ks][1], Bm, acc0, 0, 0, 0);
            acc1 = __builtin_amdgcn_mfma_f32_16x16x32_bf16(A[1][Ks][1], Bm, acc1, 0, 0, 0);
            acc0 = __builtin_amdgcn_mfma_f32_16x16x32_bf16(A[0][Ks][0], Bl, acc0, 0, 0, 0);
            acc1 = __builtin_amdgcn_mfma_f32_16x16x32_bf16(A[1][Ks][0], Bl, acc1, 0, 0, 0);
        }

        // ---- fold: score = e2 - 2*dot (z2 is row-constant, dropped) ----
#pragma unroll
        for (int v = 0; v < 4; ++v) {
            float d0 = fmaf(-2.0f, acc0[v], e2v);
            if (d0 < bestd[v]) {
                bestd[v] = d0;
                bp0 = (bp0 & ~(0xFFu << (8 * v))) | ((unsigned)t << (8 * v));
            }
            float d1 = fmaf(-2.0f, acc1[v], e2v);
            if (d1 < bestd[4 + v]) {
                bestd[4 + v] = d1;
                bp1 = (bp1 & ~(0xFFu << (8 * v))) | ((unsigned)t << (8 * v));
            }
        }
        __syncthreads();
    }

    // ---- cross-lane min over the 16 cw-lanes, then atomicMin merge ----
#pragma unroll
    for (int mt = 0; mt < 2; ++mt) {
#pragma unroll
        for (int v = 0; v < 4; ++v) {
            float bd   = bestd[mt * 4 + v];
            unsigned tt = ((mt ? bp1 : bp0) >> (8 * v)) & 0xFFu;
            int cw = chunkbase + (int)tt * 16 + l15;
            unsigned db = __float_as_uint(bd);
            db = (db & 0x80000000u) ? ~db : (db | 0x80000000u);
            unsigned long long key =
                ((unsigned long long)db << 32) | (unsigned)cw;
#pragma unroll
            for (int off = 1; off < 16; off <<= 1) {
                unsigned long long o = __shfl_xor(key, off);
                key = (o < key) ? o : key;
            }
            if (l15 == 0)
                atomicMin(&best[rowbase + mt * 16 + l4 * 4 + v], key);
        }
    }
}

// ---------------- kernel 3: gather + straight-through output + loss ---
__global__ __launch_bounds__(256) void vq_out_kernel(
    const float* __restrict__ z, const float* __restrict__ emb,
    const unsigned long long* __restrict__ best,
    float* __restrict__ out, float* __restrict__ lsum) {
    const int base = (blockIdx.x * 256 + threadIdx.x) * 8;
    const int row  = base >> 6;
    const int m    = (int)(best[row] & 0xFFFFFFFFull);

    const float4* zp = reinterpret_cast<const float4*>(z + base);
    const float4* qp = reinterpret_cast<const float4*>(emb + (size_t)m * WORD + (base & 63));
    float4* op = reinterpret_cast<float4*>(out + base);

    float s = 0.f;
#pragma unroll
    for (int i = 0; i < 2; ++i) {
        float4 zv = zp[i];
        float4 qv = qp[i];
        float dx = qv.x - zv.x, dy = qv.y - zv.y, dz = qv.z - zv.z, dw = qv.w - zv.w;
        float4 ov;
        ov.x = zv.x + dx; ov.y = zv.y + dy; ov.z = zv.z + dz; ov.w = zv.w + dw;
        op[i] = ov;
        s += dx*dx + dy*dy + dz*dz + dw*dw;
    }

#pragma unroll
    for (int off = 32; off > 0; off >>= 1) s += __shfl_down(s, off);
    __shared__ float wsum[4];
    int lane = threadIdx.x & 63, wid = threadIdx.x >> 6;
    if (lane == 0) wsum[wid] = s;
    __syncthreads();
    if (threadIdx.x == 0)
        atomicAdd(lsum, (wsum[0] + wsum[1]) + (wsum[2] + wsum[3]));
}

// ---------------- kernel 4: finalize loss -----------------------------
__global__ void vq_loss_kernel(const float* __restrict__ lsum,
                               float* __restrict__ loss_out) {
    float mean = lsum[0] * (1.0f / (float)NELEM);
    loss_out[0] = mean + 2.5f * mean;
}

extern "C" void kernel_launch(void* const* d_in, const int* in_sizes, int n_in,
                              void* d_out, int out_size, void* d_ws, size_t ws_size,
                              hipStream_t stream) {
    const float* z   = (const float*)d_in[0];   // z_mean (2048,1024)
    // d_in[1] = z_log_var, unused by the reference
    const float* emb = (const float*)d_in[2];   // (8192,64)
    float* out = (float*)d_out;                 // [z_q_st flat (2097152), loss]

    // ws layout: epack 3 MB | e2 32 KB | best 256 KB | lsum 4 B
    bf16x8* epack = (bf16x8*)d_ws;
    float*  e2    = (float*)((char*)d_ws + (size_t)PKTS * 16);
    unsigned long long* best =
        (unsigned long long*)((char*)e2 + NB_WORD * sizeof(float));
    float* lsum = (float*)((char*)best + NROWS * sizeof(unsigned long long));

    hipMemsetAsync(best, 0xFF, NROWS * sizeof(unsigned long long), stream);
    hipMemsetAsync(lsum, 0, sizeof(float), stream);

    vq_e2_kernel<<<NB_WORD / 256, 256, 0, stream>>>(emb, e2);
    vq_epack_kernel<<<PKTS / 256, 256, 0, stream>>>(emb, epack);
    vq_argmin_kernel<<<dim3(NROWS * WORD / (128 * WORD) , NCHUNK), 256, 0, stream>>>(
        z, epack, e2, best);
    vq_out_kernel<<<NELEM / (256 * 8), 256, 0, stream>>>(z, emb, best, out, lsum);
    vq_loss_kernel<<<1, 1, 0, stream>>>(lsum, out + NELEM);
}

// Round 7
// 195.053 us; speedup vs baseline: 60.6367x; 1.0506x over previous
//
#include <hip/hip_runtime.h>
#include <math.h>

#define LATENT   1024
#define WORD     64
#define NB_WORD  8192
#define BATCH    2048
#define NROWS    (BATCH * LATENT / WORD)   // 32768
#define NELEM    (BATCH * LATENT)          // 2097152

#define NCHUNK   8
#define CWCHUNK  (NB_WORD / NCHUNK)        // 1024
#define TPC      (CWCHUNK / 16)            // 64 tiles per chunk
#define NTILE    (NB_WORD / 16)            // 512 tiles
#define PKTS     (NTILE * 6 * 64)          // 196608 16B packets

typedef __attribute__((ext_vector_type(8))) __bf16 bf16x8;
typedef __attribute__((ext_vector_type(4))) float  f32x4;

// ---------------- kernel 1: e2[m] = sum_k emb[m][k]^2 (r1-proven) -----
__global__ __launch_bounds__(256) void vq_e2_kernel(
    const float* __restrict__ emb, float* __restrict__ e2) {
    int m = blockIdx.x * 256 + threadIdx.x;
    if (m >= NB_WORD) return;
    const float4* ep = reinterpret_cast<const float4*>(emb + (size_t)m * WORD);
    float s0 = 0.f, s1 = 0.f, s2 = 0.f, s3 = 0.f;
#pragma unroll
    for (int i = 0; i < 16; ++i) {
        float4 v = ep[i];
        s0 = fmaf(v.x, v.x, s0);
        s1 = fmaf(v.y, v.y, s1);
        s2 = fmaf(v.z, v.z, s2);
        s3 = fmaf(v.w, v.w, s3);
    }
    e2[m] = (s0 + s1) + (s2 + s3);
}

// ---------------- kernel 1b: pack e-splits in MFMA fragment order -----
// packet p = (tile*6 + spl*2 + Ks)*64 + lane ; 16 bytes = 8 bf16 of split
// level spl for (cw = tile*16 + (lane&15), k = Ks*32 + (lane>>4)*8 + e).
__global__ __launch_bounds__(256) void vq_epack_kernel(
    const float* __restrict__ emb, bf16x8* __restrict__ epack) {
    int p = blockIdx.x * 256 + threadIdx.x;    // 0..196607
    int lane = p & 63;
    int q    = p >> 6;
    int Ks   = q & 1;
    int r    = q >> 1;
    int spl  = r % 3;
    int tile = r / 3;
    int cw = tile * 16 + (lane & 15);
    int k0 = Ks * 32 + (lane >> 4) * 8;
    const float4* s4 = reinterpret_cast<const float4*>(emb + (size_t)cw * WORD + k0);
    float4 a = s4[0], b = s4[1];
    float tv[8] = {a.x, a.y, a.z, a.w, b.x, b.y, b.z, b.w};
    bf16x8 o;
#pragma unroll
    for (int e = 0; e < 8; ++e) {
        float v = tv[e];
        __bf16 h  = (__bf16)v;
        float r1  = v - (float)h;
        __bf16 m  = (__bf16)r1;
        float r2  = r1 - (float)m;
        __bf16 lo = (__bf16)r2;
        o[e] = (spl == 0) ? h : ((spl == 1) ? m : lo);
    }
    epack[p] = o;
}

__device__ __forceinline__ void gload_lds16(const char* g, char* l) {
    __builtin_amdgcn_global_load_lds(
        (const __attribute__((address_space(1))) void*)g,
        (__attribute__((address_space(3))) void*)l, 16, 0, 0);
}

// ---------------- kernel 2: MFMA split-bf16 argmin --------------------
// 256 thr = 4 waves; block = 128 rows x 1024-cw chunk; wave = 32 rows.
// Per iter (16 cw): DMA next tile (6 KB), 6 ds_read_b128 B-frags,
// 24 mfma_f32_16x16x32_bf16 (6 split-combos x 2 Ksteps x 2 mtiles),
// fold score = e2 - 2*dot into per-lane running argmin.
__global__ __launch_bounds__(256)
__attribute__((amdgpu_waves_per_eu(4, 8)))
void vq_argmin_kernel(
    const float* __restrict__ z, const bf16x8* __restrict__ epack,
    const float* __restrict__ e2, unsigned long long* __restrict__ best) {

    __shared__ __align__(16) char le[2 * 6144];
    __shared__ __align__(16) float le2c[CWCHUNK];   // 4 KB, whole chunk

    const int tid   = threadIdx.x;
    const int lane  = tid & 63;
    const int wband = tid >> 6;               // 0..3
    const int l15   = lane & 15;
    const int l4    = lane >> 4;              // 0..3
    const int rowbase   = blockIdx.x * 128 + wband * 32;
    const int tile0     = blockIdx.y * TPC;
    const int chunkbase = blockIdx.y * CWCHUNK;

    // ---- stage tile 0 into buf 0 ----
    {
        const char* src = (const char*)epack + (size_t)tile0 * 6144 + tid * 16;
        char* dst = le + (tid & ~63) * 16;
        gload_lds16(src, dst);
        if (tid < 128) gload_lds16(src + 4096, dst + 4096);
    }
    // ---- stage chunk e2 (1024 floats) ----
    gload_lds16((const char*)(e2 + chunkbase + tid * 4),
                (char*)le2c + (tid & ~63) * 16);

    // ---- build A-frags (z 3-way bf16 split) in registers ----
    bf16x8 A[2][2][3];                         // [mt][Ks][spl]
    const float4* zf4 = reinterpret_cast<const float4*>(z);
#pragma unroll
    for (int mt = 0; mt < 2; ++mt) {
        int row = rowbase + mt * 16 + l15;
#pragma unroll
        for (int Ks = 0; Ks < 2; ++Ks) {
            float4 v0 = zf4[(size_t)row * 16 + Ks * 8 + l4 * 2];
            float4 v1 = zf4[(size_t)row * 16 + Ks * 8 + l4 * 2 + 1];
            float tv[8] = {v0.x, v0.y, v0.z, v0.w, v1.x, v1.y, v1.z, v1.w};
#pragma unroll
            for (int e = 0; e < 8; ++e) {
                float v = tv[e];
                __bf16 h  = (__bf16)v;
                float r1  = v - (float)h;
                __bf16 m  = (__bf16)r1;
                float r2  = r1 - (float)m;
                __bf16 lo = (__bf16)r2;
                A[mt][Ks][0][e] = h;
                A[mt][Ks][1][e] = m;
                A[mt][Ks][2][e] = lo;
            }
        }
    }
    __syncthreads();    // drains both DMAs (vmcnt) + joins waves

    float bestd[8] = {INFINITY, INFINITY, INFINITY, INFINITY,
                      INFINITY, INFINITY, INFINITY, INFINITY};
    int   bt[8]    = {0, 0, 0, 0, 0, 0, 0, 0};

    for (int t = 0; t < TPC; ++t) {
        const int buf = t & 1;
        // DMA next tile into the other buffer (overlaps compute)
        if (t + 1 < TPC) {
            const char* src = (const char*)epack +
                              (size_t)(tile0 + t + 1) * 6144 + tid * 16;
            char* dst = le + (buf ^ 1) * 6144 + (tid & ~63) * 16;
            gload_lds16(src, dst);
            if (tid < 128) gload_lds16(src + 4096, dst + 4096);
        }
        float e2v = le2c[t * 16 + l15];

        f32x4 acc0 = {0.f, 0.f, 0.f, 0.f};
        f32x4 acc1 = {0.f, 0.f, 0.f, 0.f};
#pragma unroll
        for (int Ks = 0; Ks < 2; ++Ks) {
            const char* bbase = le + buf * 6144 + (size_t)Ks * 1024 + lane * 16;
            bf16x8 Bh = *reinterpret_cast<const bf16x8*>(bbase);          // spl0
            bf16x8 Bm = *reinterpret_cast<const bf16x8*>(bbase + 2048);   // spl1
            bf16x8 Bl = *reinterpret_cast<const bf16x8*>(bbase + 4096);   // spl2
            // combos: hh, mh, lh, hm, mm, hl  (x 2 row-tiles)
            acc0 = __builtin_amdgcn_mfma_f32_16x16x32_bf16(A[0][Ks][0], Bh, acc0, 0, 0, 0);
            acc1 = __builtin_amdgcn_mfma_f32_16x16x32_bf16(A[1][Ks][0], Bh, acc1, 0, 0, 0);
            acc0 = __builtin_amdgcn_mfma_f32_16x16x32_bf16(A[0][Ks][1], Bh, acc0, 0, 0, 0);
            acc1 = __builtin_amdgcn_mfma_f32_16x16x32_bf16(A[1][Ks][1], Bh, acc1, 0, 0, 0);
            acc0 = __builtin_amdgcn_mfma_f32_16x16x32_bf16(A[0][Ks][2], Bh, acc0, 0, 0, 0);
            acc1 = __builtin_amdgcn_mfma_f32_16x16x32_bf16(A[1][Ks][2], Bh, acc1, 0, 0, 0);
            acc0 = __builtin_amdgcn_mfma_f32_16x16x32_bf16(A[0][Ks][0], Bm, acc0, 0, 0, 0);
            acc1 = __builtin_amdgcn_mfma_f32_16x16x32_bf16(A[1][Ks][0], Bm, acc1, 0, 0, 0);
            acc0 = __builtin_amdgcn_mfma_f32_16x16x32_bf16(A[0][Ks][1], Bm, acc0, 0, 0, 0);
            acc1 = __builtin_amdgcn_mfma_f32_16x16x32_bf16(A[1][Ks][1], Bm, acc1, 0, 0, 0);
            acc0 = __builtin_amdgcn_mfma_f32_16x16x32_bf16(A[0][Ks][0], Bl, acc0, 0, 0, 0);
            acc1 = __builtin_amdgcn_mfma_f32_16x16x32_bf16(A[1][Ks][0], Bl, acc1, 0, 0, 0);
        }

        // ---- fold: score = e2 - 2*dot (z2 is row-constant, dropped) ----
#pragma unroll
        for (int v = 0; v < 4; ++v) {
            float d0 = fmaf(-2.0f, acc0[v], e2v);
            if (d0 < bestd[v])     { bestd[v]     = d0; bt[v]     = t; }
            float d1 = fmaf(-2.0f, acc1[v], e2v);
            if (d1 < bestd[4 + v]) { bestd[4 + v] = d1; bt[4 + v] = t; }
        }
        __syncthreads();
    }

    // ---- cross-lane min over the 16 cw-lanes, then atomicMin merge ----
#pragma unroll
    for (int mt = 0; mt < 2; ++mt) {
#pragma unroll
        for (int v = 0; v < 4; ++v) {
            float bd = bestd[mt * 4 + v];
            int   cw = chunkbase + bt[mt * 4 + v] * 16 + l15;
            unsigned db = __float_as_uint(bd);
            db = (db & 0x80000000u) ? ~db : (db | 0x80000000u);
            unsigned long long key =
                ((unsigned long long)db << 32) | (unsigned)cw;
#pragma unroll
            for (int off = 1; off < 16; off <<= 1) {
                unsigned long long o = __shfl_xor(key, off);
                key = (o < key) ? o : key;
            }
            if (l15 == 0)
                atomicMin(&best[rowbase + mt * 16 + l4 * 4 + v], key);
        }
    }
}

// ---------------- kernel 3: gather + straight-through output + loss ---
__global__ __launch_bounds__(256) void vq_out_kernel(
    const float* __restrict__ z, const float* __restrict__ emb,
    const unsigned long long* __restrict__ best,
    float* __restrict__ out, float* __restrict__ lsum) {
    const int base = (blockIdx.x * 256 + threadIdx.x) * 8;
    const int row  = base >> 6;
    const int m    = (int)(best[row] & 0xFFFFFFFFull);

    const float4* zp = reinterpret_cast<const float4*>(z + base);
    const float4* qp = reinterpret_cast<const float4*>(emb + (size_t)m * WORD + (base & 63));
    float4* op = reinterpret_cast<float4*>(out + base);

    float s = 0.f;
#pragma unroll
    for (int i = 0; i < 2; ++i) {
        float4 zv = zp[i];
        float4 qv = qp[i];
        float dx = qv.x - zv.x, dy = qv.y - zv.y, dz = qv.z - zv.z, dw = qv.w - zv.w;
        float4 ov;
        ov.x = zv.x + dx; ov.y = zv.y + dy; ov.z = zv.z + dz; ov.w = zv.w + dw;
        op[i] = ov;
        s += dx*dx + dy*dy + dz*dz + dw*dw;
    }

#pragma unroll
    for (int off = 32; off > 0; off >>= 1) s += __shfl_down(s, off);
    __shared__ float wsum[4];
    int lane = threadIdx.x & 63, wid = threadIdx.x >> 6;
    if (lane == 0) wsum[wid] = s;
    __syncthreads();
    if (threadIdx.x == 0)
        atomicAdd(lsum, (wsum[0] + wsum[1]) + (wsum[2] + wsum[3]));
}

// ---------------- kernel 4: finalize loss -----------------------------
__global__ void vq_loss_kernel(const float* __restrict__ lsum,
                               float* __restrict__ loss_out) {
    float mean = lsum[0] * (1.0f / (float)NELEM);
    loss_out[0] = mean + 2.5f * mean;
}

extern "C" void kernel_launch(void* const* d_in, const int* in_sizes, int n_in,
                              void* d_out, int out_size, void* d_ws, size_t ws_size,
                              hipStream_t stream) {
    const float* z   = (const float*)d_in[0];   // z_mean (2048,1024)
    // d_in[1] = z_log_var, unused by the reference
    const float* emb = (const float*)d_in[2];   // (8192,64)
    float* out = (float*)d_out;                 // [z_q_st flat (2097152), loss]

    // ws layout: epack 3 MB | e2 32 KB | best 256 KB | lsum 4 B
    bf16x8* epack = (bf16x8*)d_ws;
    float*  e2    = (float*)((char*)d_ws + (size_t)PKTS * 16);
    unsigned long long* best =
        (unsigned long long*)((char*)e2 + NB_WORD * sizeof(float));
    float* lsum = (float*)((char*)best + NROWS * sizeof(unsigned long long));

    hipMemsetAsync(best, 0xFF, NROWS * sizeof(unsigned long long), stream);
    hipMemsetAsync(lsum, 0, sizeof(float), stream);

    vq_e2_kernel<<<NB_WORD / 256, 256, 0, stream>>>(emb, e2);
    vq_epack_kernel<<<PKTS / 256, 256, 0, stream>>>(emb, epack);
    vq_argmin_kernel<<<dim3(NROWS / 128, NCHUNK), 256, 0, stream>>>(
        z, epack, e2, best);
    vq_out_kernel<<<NELEM / (256 * 8), 256, 0, stream>>>(z, emb, best, out, lsum);
    vq_loss_kernel<<<1, 1, 0, stream>>>(lsum, out + NELEM);
}